// Round 2
// baseline (96.706 us; speedup 1.0000x reference)
//
#include <hip/hip_runtime.h>

// TauLoss: 1 - mean_c [ sum_{i,j} sign(y[c,i]-y[c,j]) * tanh(p[c,i]-p[c,j]) / (N*(N-1)) ]
//
// Identities:
//   tanh(d*s) = s*tanh(d), s in {-1,0,1}
//   tanh(a-b) = (ta-tb)/(1-ta*tb)          -> tanh once per element, not per pair
//   summand symmetric under i<->j          -> sum = 2 * sum_{i>j}  (half the pairs)
//   s*val = val ^ signbit(l_i-l_j)          -> 3 VALU instead of 2x(cmp+cndmask);
//                                              exact except y-ties (error <1e-7 on output)
//   1 v_rcp per 4 pairs via product trick   -> rcp (16 cyc wave64) amortized to 4
//
// Single kernel: per-block partial -> global atomicAdd -> last block writes out.

#define TAU_N 1024
#define TAU_C 128
#define TILE  256
#define NTILE (TAU_N / TILE)              // 4
#define NTP   (NTILE * (NTILE + 1) / 2)   // 10 triangular tile-pairs
#define NBLK  (TAU_C * NTP)               // 1280 blocks

__device__ __constant__ int c_TI[NTP] = {0,1,1,2,2,2,3,3,3,3};
__device__ __constant__ int c_TJ[NTP] = {0,0,1,0,1,2,0,1,2,3};

__device__ __forceinline__ float sgnmul(float val, float d) {
    // val * sign(d) for d != 0; for d == +-0 returns +-val (only y-ties, negligible)
    unsigned s = __float_as_uint(d) & 0x80000000u;
    return __uint_as_float(__float_as_uint(val) ^ s);
}

__global__ __launch_bounds__(TILE) void tau_tri_kernel(
        const float* __restrict__ pred, const float* __restrict__ y,
        float* __restrict__ out, float* __restrict__ acc_ws,
        unsigned* __restrict__ cnt_ws) {
    __shared__ __align__(16) float2 rowj[TILE];   // (tanh(p), y) for the j-tile
    __shared__ float wsum[TILE / 64];

    const int bx  = blockIdx.x;
    const int c   = bx / NTP;
    const int tp  = bx % NTP;
    const int ti  = c_TI[tp];
    const int tj  = c_TJ[tp];
    const bool diag = (ti == tj);
    const int tid = threadIdx.x;

    const float* p = pred + c * TAU_N;
    const float* l = y    + c * TAU_N;

    // Stage j-tile into LDS; thread's own i-element stays in registers.
    const int jg = tj * TILE + tid;
    float2 vj;
    vj.x = tanhf(p[jg]);
    vj.y = l[jg];
    rowj[tid] = vj;

    float mt, ml;
    if (diag) {
        mt = vj.x; ml = vj.y;             // i-element == j-element for diag tiles
    } else {
        const int ig = ti * TILE + tid;
        mt = tanhf(p[ig]);
        ml = l[ig];
    }
    __syncthreads();

    // Strict lower triangle within diag tiles: local j < local i (= tid).
    const int jmax = diag ? tid : TILE;
    const float4* rowj4 = (const float4*)rowj;

    float accA = 0.f, accB = 0.f;
    int j = 0;
    for (; j + 4 <= jmax; j += 4) {
        float4 q0 = rowj4[(j >> 1) + 0];  // rowj[j],   rowj[j+1]
        float4 q1 = rowj4[(j >> 1) + 1];  // rowj[j+2], rowj[j+3]
        float n0 = mt - q0.x, n1 = mt - q0.z, n2 = mt - q1.x, n3 = mt - q1.z;
        float d0 = __builtin_fmaf(-mt, q0.x, 1.f);
        float d1 = __builtin_fmaf(-mt, q0.z, 1.f);
        float d2 = __builtin_fmaf(-mt, q1.x, 1.f);
        float d3 = __builtin_fmaf(-mt, q1.z, 1.f);
        float p01 = d0 * d1, p23 = d2 * d3;
        float inv = __builtin_amdgcn_rcpf(p01 * p23);
        float i01 = inv * p23, i23 = inv * p01;   // 1/(d0*d1), 1/(d2*d3)
        float v0 = n0 * (d1 * i01);
        float v1 = n1 * (d0 * i01);
        float v2 = n2 * (d3 * i23);
        float v3 = n3 * (d2 * i23);
        accA += sgnmul(v0, ml - q0.y);
        accB += sgnmul(v1, ml - q0.w);
        accA += sgnmul(v2, ml - q1.y);
        accB += sgnmul(v3, ml - q1.w);
    }
    for (; j < jmax; ++j) {               // diag-tile remainder (<= 3 iters)
        float2 v = rowj[j];
        float n = mt - v.x;
        float d = __builtin_fmaf(-mt, v.x, 1.f);
        float val = n * __builtin_amdgcn_rcpf(d);
        accA += sgnmul(val, ml - v.y);
    }
    float acc = accA + accB;

    // Wave reduce (64 lanes), then cross-wave, then one atomic per block.
    for (int off = 32; off >= 1; off >>= 1)
        acc += __shfl_down(acc, off, 64);
    if ((tid & 63) == 0) wsum[tid >> 6] = acc;
    __syncthreads();
    if (tid == 0) {
        float t = (wsum[0] + wsum[1]) + (wsum[2] + wsum[3]);
        atomicAdd(acc_ws, t);
        __threadfence();
        unsigned old = atomicAdd(cnt_ws, 1u);
        if (old == NBLK - 1) {            // last block: all adds are visible
            __threadfence();
            float total = atomicAdd(acc_ws, 0.0f);  // returns final sum
            const float scale = 2.0f / ((float)TAU_N * (float)(TAU_N - 1) * (float)TAU_C);
            out[0] = 1.0f - total * scale;
        }
    }
}

extern "C" void kernel_launch(void* const* d_in, const int* in_sizes, int n_in,
                              void* d_out, int out_size, void* d_ws, size_t ws_size,
                              hipStream_t stream) {
    const float* pred = (const float*)d_in[0];
    const float* y    = (const float*)d_in[1];
    float* out        = (float*)d_out;
    float* acc_ws     = (float*)d_ws;
    unsigned* cnt_ws  = (unsigned*)d_ws + 1;

    hipMemsetAsync(d_ws, 0, 2 * sizeof(unsigned), stream);  // zero acc + counter
    tau_tri_kernel<<<NBLK, TILE, 0, stream>>>(pred, y, out, acc_ws, cnt_ws);
}

// Round 3
// 93.370 us; speedup vs baseline: 1.0357x; 1.0357x over previous
//
#include <hip/hip_runtime.h>

// TauLoss: 1 - mean_c [ sum_{i,j} sign(y[c,i]-y[c,j]) * tanh(p[c,i]-p[c,j]) / (N*(N-1)) ]
//
// Identities:
//   tanh(d*s) = s*tanh(d), s in {-1,0,1}
//   tanh(a-b) = (ta-tb)/(1-ta*tb)   -> tanh once per element, not per pair
//   summand symmetric under i<->j   -> sum = 2 * sum over unordered pairs
//   s*val = val ^ signbit(l_i-l_j)  -> exact except y-ties (error <1e-7 on output)
//
// R2 lesson: batching 4 pairs into one rcp chain killed ILP (latency-bound,
// VALUBusy 36%). R3: per-pair rcp (independent chains), explicit LDS prefetch
// pipeline, and UNIFORM trip counts (diag tiles run the full 256x256 weighted
// 0.5 -- diagonal entries are exactly 0, so no masking; no divergence).

#define TAU_N 1024
#define TAU_C 128
#define TILE  256
#define NTILE (TAU_N / TILE)              // 4
#define NTP   (NTILE * (NTILE + 1) / 2)   // 10 tile-pairs (ti >= tj)
#define NBLK  (TAU_C * NTP)               // 1280 blocks

__device__ __constant__ int c_TI[NTP] = {0,1,1,2,2,2,3,3,3,3};
__device__ __constant__ int c_TJ[NTP] = {0,0,1,0,1,2,0,1,2,3};

__device__ __forceinline__ float tau_pair(float mt, float ml, float tj, float lj,
                                          float acc) {
    float n  = mt - tj;
    float d  = __builtin_fmaf(-mt, tj, 1.0f);      // 1 - mt*tj in (0,2]
    float v  = n * __builtin_amdgcn_rcpf(d);        // tanh(p_i - p_j)
    float ld = ml - lj;
    unsigned s = __float_as_uint(ld) & 0x80000000u; // sign(l_i - l_j)
    return acc + __uint_as_float(__float_as_uint(v) ^ s);
}

__global__ __launch_bounds__(TILE) void tau_tri_kernel(
        const float* __restrict__ pred, const float* __restrict__ y,
        float* __restrict__ out, float* __restrict__ acc_ws,
        unsigned* __restrict__ cnt_ws) {
    __shared__ __align__(16) float2 rowj[TILE + 8];  // +8 pad for prefetch overrun
    __shared__ float wsum[TILE / 64];

    const int bx   = blockIdx.x;
    const int c    = bx / NTP;
    const int tp   = bx % NTP;
    const int ti   = c_TI[tp];
    const int tj   = c_TJ[tp];
    const bool diag = (ti == tj);
    const int tid  = threadIdx.x;

    const float* p = pred + c * TAU_N;
    const float* l = y    + c * TAU_N;

    // Stage j-tile (tanh(p), y) into LDS; own i-element stays in registers.
    float2 vj;
    vj.x = tanhf(p[tj * TILE + tid]);
    vj.y = l[tj * TILE + tid];
    rowj[tid] = vj;
    if (tid < 8) rowj[TILE + tid] = make_float2(0.f, 0.f);  // pad (never consumed)

    float mt, ml;
    if (diag) {
        mt = vj.x; ml = vj.y;
    } else {
        mt = tanhf(p[ti * TILE + tid]);
        ml = l[ti * TILE + tid];
    }
    __syncthreads();

    // Software-pipelined j-loop: 8 pairs/body, prefetch next 8 (broadcast LDS
    // reads -- all lanes same address, conflict-free).
    const float4* r4 = (const float4*)rowj;   // r4[k] = (t[2k],y[2k],t[2k+1],y[2k+1])
    float4 q0 = r4[0], q1 = r4[1], q2 = r4[2], q3 = r4[3];
    float a0 = 0.f, a1 = 0.f, a2 = 0.f, a3 = 0.f;
#pragma unroll 2
    for (int j = 0; j < TILE; j += 8) {
        const int nb = (j >> 1) + 4;
        float4 n0 = r4[nb + 0];
        float4 n1 = r4[nb + 1];
        float4 n2 = r4[nb + 2];
        float4 n3 = r4[nb + 3];
        a0 = tau_pair(mt, ml, q0.x, q0.y, a0);
        a1 = tau_pair(mt, ml, q0.z, q0.w, a1);
        a2 = tau_pair(mt, ml, q1.x, q1.y, a2);
        a3 = tau_pair(mt, ml, q1.z, q1.w, a3);
        a0 = tau_pair(mt, ml, q2.x, q2.y, a0);
        a1 = tau_pair(mt, ml, q2.z, q2.w, a1);
        a2 = tau_pair(mt, ml, q3.x, q3.y, a2);
        a3 = tau_pair(mt, ml, q3.z, q3.w, a3);
        q0 = n0; q1 = n1; q2 = n2; q3 = n3;
    }
    float acc = (a0 + a1) + (a2 + a3);
    // Diag tiles cover each unordered pair twice (and i==j contributes 0).
    if (diag) acc *= 0.5f;

    // Wave reduce, cross-wave via LDS, one atomic per block.
    for (int off = 32; off >= 1; off >>= 1)
        acc += __shfl_down(acc, off, 64);
    if ((tid & 63) == 0) wsum[tid >> 6] = acc;
    __syncthreads();
    if (tid == 0) {
        float t = (wsum[0] + wsum[1]) + (wsum[2] + wsum[3]);
        atomicAdd(acc_ws, t);
        __threadfence();
        unsigned old = atomicAdd(cnt_ws, 1u);
        if (old == NBLK - 1) {            // last block: all adds visible
            __threadfence();
            float total = atomicAdd(acc_ws, 0.0f);
            const float scale = 2.0f / ((float)TAU_N * (float)(TAU_N - 1) * (float)TAU_C);
            out[0] = 1.0f - total * scale;
        }
    }
}

extern "C" void kernel_launch(void* const* d_in, const int* in_sizes, int n_in,
                              void* d_out, int out_size, void* d_ws, size_t ws_size,
                              hipStream_t stream) {
    const float* pred = (const float*)d_in[0];
    const float* y    = (const float*)d_in[1];
    float* out        = (float*)d_out;
    float* acc_ws     = (float*)d_ws;
    unsigned* cnt_ws  = (unsigned*)d_ws + 1;

    hipMemsetAsync(d_ws, 0, 2 * sizeof(unsigned), stream);  // zero acc + counter
    tau_tri_kernel<<<NBLK, TILE, 0, stream>>>(pred, y, out, acc_ws, cnt_ws);
}